// Round 5
// baseline (144.826 us; speedup 1.0000x reference)
//
#include <hip/hip_runtime.h>
#include <hip/hip_cooperative_groups.h>
#include <stdint.h>

namespace cg = cooperative_groups;

#define N_PROP    262144
#define N_GT      128
#define N_ALL     (N_PROP + N_GT)      // 262272
#define NFG_MAX   128
#define NROIS_OUT 512
#define BLK       256
#define NBLOCKS   ((N_ALL + BLK - 1) / BLK)   // 1025

// ws: cnt uint32[NBLOCKS] @ 0
#define OFF_CNT 0

// One IoU step, byte-identical rounding to the reference (no FMA contraction).
#define IOU_STEP(gv, gav, jidx)                                                        \
    {                                                                                  \
        float iw = fmaxf(__fadd_rn(__fsub_rn(fminf(b.z, (gv).z), fmaxf(b.x, (gv).x)), 1.0f), 0.0f); \
        float ih = fmaxf(__fadd_rn(__fsub_rn(fminf(b.w, (gv).w), fmaxf(b.y, (gv).y)), 1.0f), 0.0f); \
        float inter = __fmul_rn(iw, ih);                                               \
        float denom = __fsub_rn(__fadd_rn(a, (gav)), inter);                           \
        float iou = __fdiv_rn(inter, denom);                                           \
        if (iou > best) { best = iou; bestj = (jidx); }                                \
    }

__global__ __launch_bounds__(BLK) void k_fused(
    const float* __restrict__ rois, const float* __restrict__ gt,
    const int* __restrict__ labels, uint32_t* __restrict__ cnt,
    float* __restrict__ out)
{
    __shared__ float sga[N_GT];
    __shared__ int sF[4], sB[4];
    __shared__ int sTF[4], sTB[4], sPF[4], sPB[4], sWF[4], sWB[4];
    int tid = threadIdx.x, bid = blockIdx.x;
    int lane = tid & 63, w = tid >> 6;

    // ---- stage GT areas in LDS (coords read uniformly from global -> scalar pipe)
    if (tid < N_GT) {
        float4 g = *reinterpret_cast<const float4*>(gt + 4 * tid);
        sga[tid] = __fmul_rn(__fadd_rn(__fsub_rn(g.z, g.x), 1.0f),
                             __fadd_rn(__fsub_rn(g.w, g.y), 1.0f));
    }
    __syncthreads();

    // ---- phase A: per-roi max/argmax IoU
    int i = bid * BLK + tid;
    bool v = (i < N_ALL);
    float4 b = {0.f, 0.f, 0.f, 0.f};
    if (v) {
        const float* p = (i < N_PROP) ? (rois + 4 * (size_t)i)
                                      : (gt + 4 * (size_t)(i - N_PROP));
        b = *reinterpret_cast<const float4*>(p);
    }
    float a = __fmul_rn(__fadd_rn(__fsub_rn(b.z, b.x), 1.0f),
                        __fadd_rn(__fsub_rn(b.w, b.y), 1.0f));

    float best = -1.0f; int bestj = 0;
    const float4* gtv  = reinterpret_cast<const float4*>(gt);
    const float4* sgaV = reinterpret_cast<const float4*>(sga);
    #pragma unroll 2
    for (int jj = 0; jj < N_GT / 4; ++jj) {
        float4 ga4 = sgaV[jj];                 // one ds_read_b128 per 4 GT (broadcast)
        float4 g0 = gtv[4 * jj + 0];           // uniform -> scalar loads
        float4 g1 = gtv[4 * jj + 1];
        float4 g2 = gtv[4 * jj + 2];
        float4 g3 = gtv[4 * jj + 3];
        IOU_STEP(g0, ga4.x, 4 * jj + 0);       // ascending j: strict > == first-max
        IOU_STEP(g1, ga4.y, 4 * jj + 1);
        IOU_STEP(g2, ga4.z, 4 * jj + 2);
        IOU_STEP(g3, ga4.w, 4 * jj + 3);
    }

    bool fg = v && (best > 0.5f);
    bool bg = v && (best > 0.1f) && (best < 0.5f);

    unsigned long long mf = __ballot(fg ? 1 : 0);
    unsigned long long mb = __ballot(bg ? 1 : 0);
    if (lane == 0) { sF[w] = __popcll(mf); sB[w] = __popcll(mb); }
    __syncthreads();
    if (tid == 0)
        cnt[bid] = ((uint32_t)(sB[0] + sB[1] + sB[2] + sB[3]) << 16)
                 |  (uint32_t)(sF[0] + sF[1] + sF[2] + sF[3]);

    // ---- grid-wide barrier (flags/argmax/coords stay in registers)
    __threadfence();
    cg::this_grid().sync();

    // ---- phase B: global totals + prefix(< bid) over block counts (4 KB, L2-hot)
    int totF = 0, totB = 0, preF = 0, preB = 0;
    for (int j = tid; j < NBLOCKS; j += BLK) {
        uint32_t c = cnt[j];
        int f = (int)(c & 0xFFFFu), bb = (int)(c >> 16);
        totF += f; totB += bb;
        if (j < bid) { preF += f; preB += bb; }
    }
    #pragma unroll
    for (int off = 32; off > 0; off >>= 1) {
        totF += __shfl_down(totF, off, 64);
        totB += __shfl_down(totB, off, 64);
        preF += __shfl_down(preF, off, 64);
        preB += __shfl_down(preB, off, 64);
    }
    if (lane == 0) { sTF[w] = totF; sTB[w] = totB; sPF[w] = preF; sPB[w] = preB; }

    unsigned long long mf2 = __ballot(fg ? 1 : 0);
    unsigned long long mb2 = __ballot(bg ? 1 : 0);
    unsigned long long lemask = (lane == 63) ? ~0ull : ((1ull << (lane + 1)) - 1ull);
    int inclF = __popcll(mf2 & lemask);
    int inclB = __popcll(mb2 & lemask);
    if (lane == 0) { sWF[w] = __popcll(mf2); sWB[w] = __popcll(mb2); }
    __syncthreads();

    totF = sTF[0] + sTF[1] + sTF[2] + sTF[3];
    totB = sTB[0] + sTB[1] + sTB[2] + sTB[3];
    preF = sPF[0] + sPF[1] + sPF[2] + sPF[3];
    preB = sPB[0] + sPB[1] + sPB[2] + sPB[3];
    int wPreF = 0, wPreB = 0;
    for (int k = 0; k < 4; ++k) {
        if (k < w) { wPreF += sWF[k]; wPreB += sWB[k]; }
    }
    if (!v) return;

    int NF  = totF < NFG_MAX ? totF : NFG_MAX;
    int LIM = NROIS_OUT - NF;
    int NB  = totB < LIM ? totB : LIM;

    int fgCum = preF + wPreF + inclF;
    int bgCum = preB + wPreB + inclB;

    int pos;
    if (fg && fgCum <= NFG_MAX) {
        pos = fgCum - 1;
    } else if (bg && bgCum <= LIM) {
        pos = NF + bgCum - 1;
    } else {
        int selF = fgCum < NFG_MAX ? fgCum : NFG_MAX;
        int selB = bgCum < LIM ? bgCum : LIM;
        int restCum = (i + 1) - selF - selB;
        pos = NF + NB + restCum - 1;
    }
    if (pos >= NROIS_OUT) return;

    float4 gb = gtv[bestj];

    float wdt = __fadd_rn(__fsub_rn(b.z, b.x), 1.0f);
    float hgt = __fadd_rn(__fsub_rn(b.w, b.y), 1.0f);
    float cx  = __fadd_rn(b.x, __fmul_rn(0.5f, wdt));
    float cy  = __fadd_rn(b.y, __fmul_rn(0.5f, hgt));
    float gw  = __fadd_rn(__fsub_rn(gb.z, gb.x), 1.0f);
    float gh  = __fadd_rn(__fsub_rn(gb.w, gb.y), 1.0f);
    float gcx = __fadd_rn(gb.x, __fmul_rn(0.5f, gw));
    float gcy = __fadd_rn(gb.y, __fmul_rn(0.5f, gh));

    float d0 = __fdiv_rn(__fdiv_rn(__fsub_rn(gcx, cx), wdt), 0.2f);
    float d1 = __fdiv_rn(__fdiv_rn(__fsub_rn(gcy, cy), hgt), 0.2f);
    float d2 = __fdiv_rn(logf(__fdiv_rn(gw, wdt)), 0.2f);
    float d3 = __fdiv_rn(logf(__fdiv_rn(gh, hgt)), 0.2f);

    out[4 * pos + 0] = b.x;
    out[4 * pos + 1] = b.y;
    out[4 * pos + 2] = b.z;
    out[4 * pos + 3] = b.w;
    out[2048 + 4 * pos + 0] = d0;
    out[2048 + 4 * pos + 1] = d1;
    out[2048 + 4 * pos + 2] = d2;
    out[2048 + 4 * pos + 3] = d3;
    out[4096 + pos] = (float)labels[bestj];
}

extern "C" void kernel_launch(void* const* d_in, const int* in_sizes, int n_in,
                              void* d_out, int out_size, void* d_ws, size_t ws_size,
                              hipStream_t stream)
{
    const float* rois   = (const float*)d_in[0];
    const float* gt     = (const float*)d_in[1];
    const int*   labels = (const int*)d_in[2];
    float* out = (float*)d_out;
    uint32_t* cnt = (uint32_t*)((char*)d_ws + OFF_CNT);

    void* args[] = { (void*)&rois, (void*)&gt, (void*)&labels, (void*)&cnt, (void*)&out };
    hipLaunchCooperativeKernel((const void*)k_fused, dim3(NBLOCKS), dim3(BLK),
                               args, 0, stream);
}

// Round 6
// 39.780 us; speedup vs baseline: 3.6407x; 3.6407x over previous
//
#include <hip/hip_runtime.h>
#include <stdint.h>

#define N_PROP    262144
#define N_GT      128
#define N_ALL     (N_PROP + N_GT)      // 262272
#define NFG_MAX   128
#define NROIS_OUT 512
#define BLK       256
#define ITEMS1    128                  // items per k_iou block (2 threads/item)
#define NB1       (N_ALL / ITEMS1)     // 2049 (exact)
#define NCNT      NB1                  // cnt chunks of 128 items
#define NB2       ((N_ALL + BLK - 1) / BLK)   // 1025 k_select blocks (256 items)

// ---------------- workspace layout (bytes) ----------------
// packed : uint16 [N_ALL]  @ 0        ((flag<<8)|argmax)
// cnt    : uint32 [NCNT]   @ 524544   ((bg<<16)|fg per 128-item chunk)
#define OFF_PACKED 0
#define OFF_CNT    524544

// One IoU step, byte-identical rounding to the reference (no FMA contraction).
#define IOU_STEP(gv, gav, jidx)                                                        \
    {                                                                                  \
        float iw = fmaxf(__fadd_rn(__fsub_rn(fminf(b.z, (gv).z), fmaxf(b.x, (gv).x)), 1.0f), 0.0f); \
        float ih = fmaxf(__fadd_rn(__fsub_rn(fminf(b.w, (gv).w), fmaxf(b.y, (gv).y)), 1.0f), 0.0f); \
        float inter = __fmul_rn(iw, ih);                                               \
        float denom = __fsub_rn(__fadd_rn(a, (gav)), inter);                           \
        float iou = __fdiv_rn(inter, denom);                                           \
        if (iou > best) { best = iou; bestj = (jidx); }                                \
    }

// K1: 2 threads per item; lower half scans GT j=0..63, upper half j=64..127.
// Merge keeps smaller-j on ties == global first-max (jnp.argmax). 32 waves/CU.
__global__ __launch_bounds__(BLK) void k_iou(
    const float* __restrict__ rois, const float* __restrict__ gt,
    uint16_t* __restrict__ packed, uint32_t* __restrict__ cnt)
{
    __shared__ float sga[N_GT];
    __shared__ float sBest[ITEMS1];
    __shared__ int   sBj[ITEMS1];
    __shared__ int   sF[2], sB[2];

    int tid = threadIdx.x;
    int half = tid >> 7;          // 0 = j 0..63, 1 = j 64..127
    int li   = tid & 127;         // item index within block

    if (tid < N_GT) {
        float4 g = *reinterpret_cast<const float4*>(gt + 4 * tid);
        sga[tid] = __fmul_rn(__fadd_rn(__fsub_rn(g.z, g.x), 1.0f),
                             __fadd_rn(__fsub_rn(g.w, g.y), 1.0f));
    }
    __syncthreads();

    int i = blockIdx.x * ITEMS1 + li;      // always < N_ALL (exact tiling)
    const float* p = (i < N_PROP) ? (rois + 4 * (size_t)i)
                                  : (gt + 4 * (size_t)(i - N_PROP));
    float4 b = *reinterpret_cast<const float4*>(p);
    float a = __fmul_rn(__fadd_rn(__fsub_rn(b.z, b.x), 1.0f),
                        __fadd_rn(__fsub_rn(b.w, b.y), 1.0f));

    float best = -1.0f; int bestj = half * 64;
    const float4* gtv  = reinterpret_cast<const float4*>(gt);
    const float4* sgaV = reinterpret_cast<const float4*>(sga);
    int jjBase = half * 16;                // 16 groups of 4 GT per half
    #pragma unroll 2
    for (int jj = 0; jj < 16; ++jj) {
        int jg = jjBase + jj;
        float4 ga4 = sgaV[jg];             // ds_read_b128, wave-broadcast
        float4 g0 = gtv[4 * jg + 0];       // wave-uniform -> scalar-pipe candidates
        float4 g1 = gtv[4 * jg + 1];
        float4 g2 = gtv[4 * jg + 2];
        float4 g3 = gtv[4 * jg + 3];
        IOU_STEP(g0, ga4.x, 4 * jg + 0);   // ascending j: strict > == first-max
        IOU_STEP(g1, ga4.y, 4 * jg + 1);
        IOU_STEP(g2, ga4.z, 4 * jg + 2);
        IOU_STEP(g3, ga4.w, 4 * jg + 3);
    }

    if (half) { sBest[li] = best; sBj[li] = bestj; }
    __syncthreads();

    if (!half) {
        float bh = sBest[li]; int jh = sBj[li];
        if (bh > best) { best = bh; bestj = jh; }   // tie -> lower half (smaller j)

        bool fg = best > 0.5f;
        bool bg = (best > 0.1f) && (best < 0.5f);
        packed[i] = (uint16_t)(((fg ? 0 : (bg ? 1 : 2)) << 8) | bestj);

        unsigned long long mf = __ballot(fg ? 1 : 0);   // waves 0,1 fully active
        unsigned long long mb = __ballot(bg ? 1 : 0);
        int lane = tid & 63, w = tid >> 6;              // w in {0,1}
        if (lane == 0) { sF[w] = __popcll(mf); sB[w] = __popcll(mb); }
    }
    __syncthreads();
    if (tid == 0)
        cnt[blockIdx.x] = ((uint32_t)(sB[0] + sB[1]) << 16)
                        |  (uint32_t)(sF[0] + sF[1]);
}

// K2: per-block redundant global prefix over 128-item chunk counts + in-block
// ballot scan; stable-argsort position reconstruction + gather + transform.
__global__ __launch_bounds__(BLK) void k_select(
    const float* __restrict__ rois, const float* __restrict__ gt,
    const int* __restrict__ labels,
    const uint16_t* __restrict__ packed, const uint32_t* __restrict__ cnt,
    float* __restrict__ out)
{
    int tid = threadIdx.x, bid = blockIdx.x;
    int i = bid * BLK + tid;
    bool valid = (i < N_ALL);
    uint16_t p = valid ? packed[i] : (uint16_t)(2 << 8);
    int flagv = p >> 8;
    int g = p & 0xFF;
    bool isfg = valid && (flagv == 0);
    bool isbg = valid && (flagv == 1);

    // totals + prefix over chunks j < 2*bid (each chunk = 128 items, L2-hot)
    int totF = 0, totB = 0, preF = 0, preB = 0;
    for (int j = tid; j < NCNT; j += BLK) {
        uint32_t c = cnt[j];
        int f = (int)(c & 0xFFFFu), bb = (int)(c >> 16);
        totF += f; totB += bb;
        if (j < 2 * bid) { preF += f; preB += bb; }
    }
    #pragma unroll
    for (int off = 32; off > 0; off >>= 1) {
        totF += __shfl_down(totF, off, 64);
        totB += __shfl_down(totB, off, 64);
        preF += __shfl_down(preF, off, 64);
        preB += __shfl_down(preB, off, 64);
    }
    __shared__ int sTF[4], sTB[4], sPF[4], sPB[4];
    __shared__ int sWF[4], sWB[4];
    int lane = tid & 63, w = tid >> 6;
    if (lane == 0) { sTF[w] = totF; sTB[w] = totB; sPF[w] = preF; sPB[w] = preB; }

    unsigned long long mf = __ballot(isfg ? 1 : 0);
    unsigned long long mb = __ballot(isbg ? 1 : 0);
    unsigned long long lemask = (lane == 63) ? ~0ull : ((1ull << (lane + 1)) - 1ull);
    int inclF = __popcll(mf & lemask);
    int inclB = __popcll(mb & lemask);
    if (lane == 0) { sWF[w] = __popcll(mf); sWB[w] = __popcll(mb); }
    __syncthreads();

    totF = sTF[0] + sTF[1] + sTF[2] + sTF[3];
    totB = sTB[0] + sTB[1] + sTB[2] + sTB[3];
    preF = sPF[0] + sPF[1] + sPF[2] + sPF[3];
    preB = sPB[0] + sPB[1] + sPB[2] + sPB[3];
    int wPreF = 0, wPreB = 0;
    for (int k = 0; k < 4; ++k) {
        if (k < w) { wPreF += sWF[k]; wPreB += sWB[k]; }
    }
    if (!valid) return;

    int NF  = totF < NFG_MAX ? totF : NFG_MAX;
    int LIM = NROIS_OUT - NF;
    int NB  = totB < LIM ? totB : LIM;

    int fgCum = preF + wPreF + inclF;
    int bgCum = preB + wPreB + inclB;

    int pos;
    if (isfg && fgCum <= NFG_MAX) {
        pos = fgCum - 1;
    } else if (isbg && bgCum <= LIM) {
        pos = NF + bgCum - 1;
    } else {
        int selF = fgCum < NFG_MAX ? fgCum : NFG_MAX;
        int selB = bgCum < LIM ? bgCum : LIM;
        int restCum = (i + 1) - selF - selB;
        pos = NF + NB + restCum - 1;
    }
    if (pos >= NROIS_OUT) return;

    const float* rp = (i < N_PROP) ? (rois + 4 * (size_t)i)
                                   : (gt + 4 * (size_t)(i - N_PROP));
    float4 r = *reinterpret_cast<const float4*>(rp);
    float4 gb = *reinterpret_cast<const float4*>(gt + 4 * (size_t)g);

    float wdt = __fadd_rn(__fsub_rn(r.z, r.x), 1.0f);
    float hgt = __fadd_rn(__fsub_rn(r.w, r.y), 1.0f);
    float cx  = __fadd_rn(r.x, __fmul_rn(0.5f, wdt));
    float cy  = __fadd_rn(r.y, __fmul_rn(0.5f, hgt));
    float gw  = __fadd_rn(__fsub_rn(gb.z, gb.x), 1.0f);
    float gh  = __fadd_rn(__fsub_rn(gb.w, gb.y), 1.0f);
    float gcx = __fadd_rn(gb.x, __fmul_rn(0.5f, gw));
    float gcy = __fadd_rn(gb.y, __fmul_rn(0.5f, gh));

    float d0 = __fdiv_rn(__fdiv_rn(__fsub_rn(gcx, cx), wdt), 0.2f);
    float d1 = __fdiv_rn(__fdiv_rn(__fsub_rn(gcy, cy), hgt), 0.2f);
    float d2 = __fdiv_rn(logf(__fdiv_rn(gw, wdt)), 0.2f);
    float d3 = __fdiv_rn(logf(__fdiv_rn(gh, hgt)), 0.2f);

    out[4 * pos + 0] = r.x;
    out[4 * pos + 1] = r.y;
    out[4 * pos + 2] = r.z;
    out[4 * pos + 3] = r.w;
    out[2048 + 4 * pos + 0] = d0;
    out[2048 + 4 * pos + 1] = d1;
    out[2048 + 4 * pos + 2] = d2;
    out[2048 + 4 * pos + 3] = d3;
    out[4096 + pos] = (float)labels[g];
}

extern "C" void kernel_launch(void* const* d_in, const int* in_sizes, int n_in,
                              void* d_out, int out_size, void* d_ws, size_t ws_size,
                              hipStream_t stream)
{
    const float* rois   = (const float*)d_in[0];
    const float* gt     = (const float*)d_in[1];
    const int*   labels = (const int*)d_in[2];
    float* out = (float*)d_out;

    char* ws = (char*)d_ws;
    uint16_t* packed = (uint16_t*)(ws + OFF_PACKED);
    uint32_t* cnt    = (uint32_t*)(ws + OFF_CNT);

    k_iou<<<NB1, BLK, 0, stream>>>(rois, gt, packed, cnt);
    k_select<<<NB2, BLK, 0, stream>>>(rois, gt, labels, packed, cnt, out);
}